// Round 8
// baseline (1773.703 us; speedup 1.0000x reference)
//
#include <hip/hip_runtime.h>
#include <stdint.h>

#define E4M3_MAX 448.0f

typedef float f32x4 __attribute__((ext_vector_type(4)));
typedef int   i32x4 __attribute__((ext_vector_type(4)));
typedef int   i32x8 __attribute__((ext_vector_type(8)));

// ---------------------------------------------------------------------------
// async global -> LDS, 16 bytes per lane. LDS dest stays LINEAR (HW
// constraint); T2 swizzle applied by pre-swizzling the GLOBAL source column
// and swizzling the LDS READ offset with the same involution (rule #21).
// ---------------------------------------------------------------------------
__device__ __forceinline__ void gload_lds16(const void* g, void* l) {
    __builtin_amdgcn_global_load_lds(
        (__attribute__((address_space(1))) void*)(void*)g,
        (__attribute__((address_space(3))) void*)l,
        16, 0, 0);
}

__device__ __forceinline__ uint32_t quant4(float a, float b, float c, float d) {
    a = fminf(fmaxf(a, -E4M3_MAX), E4M3_MAX);
    b = fminf(fmaxf(b, -E4M3_MAX), E4M3_MAX);
    c = fminf(fmaxf(c, -E4M3_MAX), E4M3_MAX);
    d = fminf(fmaxf(d, -E4M3_MAX), E4M3_MAX);
    int q = 0;
    q = __builtin_amdgcn_cvt_pk_fp8_f32(a, b, q, false);
    q = __builtin_amdgcn_cvt_pk_fp8_f32(c, d, q, true);
    return (uint32_t)q;
}

__global__ void quant_x_kernel(const float* __restrict__ x,
                               const float* __restrict__ scale_p,
                               uint4* __restrict__ xq, int n16) {
    const float inv = 1.0f / scale_p[0];
    const int stride = gridDim.x * blockDim.x;
    for (int i = blockIdx.x * blockDim.x + threadIdx.x; i < n16; i += stride) {
        const float4* p = (const float4*)x + (size_t)i * 4;
        float4 v0 = p[0], v1 = p[1], v2 = p[2], v3 = p[3];
        uint4 q;
        q.x = quant4(v0.x * inv, v0.y * inv, v0.z * inv, v0.w * inv);
        q.y = quant4(v1.x * inv, v1.y * inv, v1.z * inv, v1.w * inv);
        q.z = quant4(v2.x * inv, v2.y * inv, v2.z * inv, v2.w * inv);
        q.w = quant4(v3.x * inv, v3.y * inv, v3.z * inv, v3.w * inv);
        xq[i] = q;
    }
}

// ---------------------------------------------------------------------------
// quantize w into MFMA-FRAGMENT-SHUFFLED layout so the GEMM can load B
// fragments directly global->register with perfectly coalesced dwordx4.
// Element (n, k):  nf=n>>4, r=n&15, kt=k>>7, kg=(k>>5)&3, koff=k&31
//   dst_byte = ((nf*nkt + kt)*64 + kg*16 + r)*32 + koff
// ---------------------------------------------------------------------------
__global__ void quant_w_kernel(const float* __restrict__ w,
                               const float* __restrict__ wsc,
                               uint8_t* __restrict__ wq,
                               int Nrows, int K, int chunkRows) {
    const int nkt = K >> 7;
    const int n32 = Nrows * (K >> 5);
    const int stride = gridDim.x * blockDim.x;
    for (int i = blockIdx.x * blockDim.x + threadIdx.x; i < n32; i += stride) {
        const int n  = i % Nrows;
        const int k0 = (i / Nrows) << 5;
        const float inv = 1.0f / wsc[n / chunkRows];
        const float4* p = (const float4*)(w + (size_t)n * K + k0);
        uint4 qa, qb;
        {
            float4 v0 = p[0], v1 = p[1], v2 = p[2], v3 = p[3];
            qa.x = quant4(v0.x * inv, v0.y * inv, v0.z * inv, v0.w * inv);
            qa.y = quant4(v1.x * inv, v1.y * inv, v1.z * inv, v1.w * inv);
            qa.z = quant4(v2.x * inv, v2.y * inv, v2.z * inv, v2.w * inv);
            qa.w = quant4(v3.x * inv, v3.y * inv, v3.z * inv, v3.w * inv);
        }
        {
            float4 v0 = p[4], v1 = p[5], v2 = p[6], v3 = p[7];
            qb.x = quant4(v0.x * inv, v0.y * inv, v0.z * inv, v0.w * inv);
            qb.y = quant4(v1.x * inv, v1.y * inv, v1.z * inv, v1.w * inv);
            qb.z = quant4(v2.x * inv, v2.y * inv, v2.z * inv, v2.w * inv);
            qb.w = quant4(v3.x * inv, v3.y * inv, v3.z * inv, v3.w * inv);
        }
        const int kt = k0 >> 7, kg = (k0 >> 5) & 3, r = n & 15, nf = n >> 4;
        uint8_t* dst = wq + (((size_t)nf * nkt + kt) * 64 + kg * 16 + r) * 32;
        *(uint4*)dst = qa;
        *(uint4*)(dst + 16) = qb;
    }
}

__device__ __forceinline__ i32x8 read_frag(const uint8_t* base, int o0, int o1) {
    i32x4 lo = *(const i32x4*)(base + o0);
    i32x4 hi = *(const i32x4*)(base + o1);
    return __builtin_shufflevector(lo, hi, 0, 1, 2, 3, 4, 5, 6, 7);
}

#define MFMA_MX(a, b, c) \
    __builtin_amdgcn_mfma_scale_f32_16x16x128_f8f6f4( \
        (a), (b), (c), 0, 0, 0, 0x7F7F7F7F, 0, 0x7F7F7F7F)

#define WAIT_LGKM(n)                                            \
    do {                                                        \
        asm volatile("s_waitcnt lgkmcnt(" #n ")" ::: "memory"); \
        __builtin_amdgcn_sched_barrier(0);                      \
    } while (0)

#define WAIT_VM(n)                                              \
    do {                                                        \
        asm volatile("s_waitcnt vmcnt(" #n ")" ::: "memory");   \
        __builtin_amdgcn_sched_barrier(0);                      \
    } while (0)

// ---------------------------------------------------------------------------
// fp8-MX GEMM, 256x256 tile, 8 waves (2Mx4N), wave-tile 128x64.
// Round-8: B in registers with ONE-TILE-AHEAD prefetch (double-buffered
// bv0/bv1, static indexing via 2x-unrolled K loop). A in double-buffered
// LDS (64 KB). vmcnt discipline (issue order: stage 4, B 8):
//   g0:        vmcnt(12) -> retires B(t) only; stage+B(t+1) stay in flight
//   end-of-it: vmcnt(8)  -> retires stage(t+1); B(t+1) crosses the barrier
// A ds_read pipeline: 2-pair depth, lgkm(4) cadence (keeps VGPR <= budget).
// ---------------------------------------------------------------------------
#define BM 256
#define BN 256
#define BKB 128

__global__ __launch_bounds__(512, 1) void gemm_fp8_kernel(
    const uint8_t* __restrict__ Aq, const uint8_t* __restrict__ Bq,
    const float* __restrict__ bias, const float* __restrict__ isp,
    const float* __restrict__ wsc, float* __restrict__ out,
    int M, int N, int K, int ocPerChunk) {
    __shared__ __align__(16) uint8_t As[2][BM * BKB];   // A only, 2 x 32 KB

    const int tid  = threadIdx.x;
    const int lane = tid & 63;
    const int wid  = tid >> 6;   // 0..7
    const int wm   = wid >> 2;   // 0..1  (M half)
    const int wn   = wid & 3;    // 0..3  (N quarter)

    // T1 XCD swizzle, by-inner chunking: consecutive blocks on an XCD share
    // bx -> the XCD's CUs work on few B-panels (L2-fit).
    const int nbx   = N / BN;
    const int nby   = M / BM;
    const int chunk = nby >> 3;            // by-rows per XCD
    const int xcd   = blockIdx.x & 7;
    const int local = blockIdx.x >> 3;
    const int bx    = local / chunk;
    const int by    = xcd * chunk + (local % chunk);
    const int m0    = by * BM;
    const int n0    = bx * BN;

    const int lr   = lane & 15;
    const int sw   = (lr & 7) << 4;
    const int off0 = ((lane >> 4) * 32) ^ sw;
    const int off1 = off0 ^ 16;

    f32x4 acc[8][4] = {};

    const int nkt = K / BKB;

    // B fragment base: frag ni of wave wn at tile t lives at
    // bbase + (ni*nkt + t)*2048, lane-contiguous 32 B.
    const uint8_t* bbase =
        Bq + ((size_t)((n0 >> 4) + wn * 4) * nkt) * 2048 + lane * 32;

    // stage A K-tile (k-offset kt) into buffer b: 4 x gload_lds16 per thread
    auto stage = [&](int b, int kt) {
#pragma unroll
        for (int i = 0; i < 4; ++i) {
            const int idx = i * 512 + tid;                 // 0..2047
            const int row = idx >> 3;                      // 0..255
            const int col = ((idx & 7) * 16) ^ ((row & 7) << 4);
            gload_lds16(Aq + (size_t)(m0 + row) * K + kt + col,
                        &As[b][0] + idx * 16);
        }
    };

    auto load_b = [&](i32x8 (&bv)[4], int t) {
#pragma unroll
        for (int ni = 0; ni < 4; ni++) {
            const uint8_t* p = bbase + ((size_t)ni * nkt + t) * 2048;
            i32x4 lo = *(const i32x4*)p;
            i32x4 hi = *(const i32x4*)(p + 16);
            bv[ni] = __builtin_shufflevector(lo, hi, 0, 1, 2, 3, 4, 5, 6, 7);
        }
    };

    i32x8 bv0[4], bv1[4];

    // prologue: A tile 0 -> LDS, B tile 0 -> bv0
    stage(0, 0);
    load_b(bv0, 0);
    asm volatile("s_waitcnt vmcnt(0)" ::: "memory");
    __builtin_amdgcn_s_barrier();

    // one K-tile iteration; bvc = B(t) (ready after vmcnt), bvn <- B(t+1)
    auto tile_iter = [&](int t, i32x8 (&bvc)[4], i32x8 (&bvn)[4]) {
        const int  cur = t & 1;
        const bool pre = (t + 1 < nkt);
        const uint8_t* pa = &As[cur][0] + (wm * 128 + lr) * BKB;

        // ---- issue next-tile staging FIRST (oldest vmem), then B(t+1) ----
        if (pre) {
            stage(cur ^ 1, (t + 1) * BKB);
            __builtin_amdgcn_sched_barrier(0);
            load_b(bvn, t + 1);
            __builtin_amdgcn_sched_barrier(0);
        }

        // ---- A pairs 0,1 (8 ds_read_b128) ----
        i32x8 a0 = read_frag(pa,            off0, off1);
        i32x8 a1 = read_frag(pa + 16 * BKB, off0, off1);
        i32x8 a2 = read_frag(pa + 32 * BKB, off0, off1);
        i32x8 a3 = read_frag(pa + 48 * BKB, off0, off1);

        // ---- g0: B(t) retired (12 = stage4 + B(t+1)8 still in flight) ----
        if (pre) { WAIT_VM(12); } else { WAIT_VM(0); }
        WAIT_LGKM(4);
        __builtin_amdgcn_s_setprio(1);
#pragma unroll
        for (int ni = 0; ni < 4; ni++) {
            acc[0][ni] = MFMA_MX(a0, bvc[ni], acc[0][ni]);
            acc[1][ni] = MFMA_MX(a1, bvc[ni], acc[1][ni]);
        }
        __builtin_amdgcn_s_setprio(0);

        // ---- g1: issue pair2, wait pair1 ----
        i32x8 a4 = read_frag(pa + 64 * BKB, off0, off1);
        i32x8 a5 = read_frag(pa + 80 * BKB, off0, off1);
        WAIT_LGKM(4);
        __builtin_amdgcn_s_setprio(1);
#pragma unroll
        for (int ni = 0; ni < 4; ni++) {
            acc[2][ni] = MFMA_MX(a2, bvc[ni], acc[2][ni]);
            acc[3][ni] = MFMA_MX(a3, bvc[ni], acc[3][ni]);
        }
        __builtin_amdgcn_s_setprio(0);

        // ---- g2: issue pair3, wait pair2 ----
        i32x8 a6 = read_frag(pa + 96 * BKB,  off0, off1);
        i32x8 a7 = read_frag(pa + 112 * BKB, off0, off1);
        WAIT_LGKM(4);
        __builtin_amdgcn_s_setprio(1);
#pragma unroll
        for (int ni = 0; ni < 4; ni++) {
            acc[4][ni] = MFMA_MX(a4, bvc[ni], acc[4][ni]);
            acc[5][ni] = MFMA_MX(a5, bvc[ni], acc[5][ni]);
        }
        __builtin_amdgcn_s_setprio(0);

        // ---- g3: wait pair3 (all tile-t LDS reads retired after this) ----
        WAIT_LGKM(0);
        __builtin_amdgcn_s_setprio(1);
#pragma unroll
        for (int ni = 0; ni < 4; ni++) {
            acc[6][ni] = MFMA_MX(a6, bvc[ni], acc[6][ni]);
            acc[7][ni] = MFMA_MX(a7, bvc[ni], acc[7][ni]);
        }
        __builtin_amdgcn_s_setprio(0);

        // ---- end: retire stage(t+1); B(t+1) stays in flight over barrier --
        if (pre) { WAIT_VM(8); } else { WAIT_VM(0); }
        __builtin_amdgcn_s_barrier();
    };

    for (int t = 0; t < nkt; t += 2) {
        tile_iter(t,     bv0, bv1);
        tile_iter(t + 1, bv1, bv0);
    }

    // ---- epilogue: dequant + bias (C/D: col=lane&15, row=(lane>>4)*4+j) ----
    const float is = isp[0];
#pragma unroll
    for (int ni = 0; ni < 4; ni++) {
        const int cidx = n0 + wn * 64 + ni * 16 + lr;
        const float sc = is * wsc[cidx / ocPerChunk];
        const float bs = bias[cidx];
#pragma unroll
        for (int mi = 0; mi < 8; mi++) {
            const int rbase = m0 + wm * 128 + mi * 16 + (lane >> 4) * 4;
#pragma unroll
            for (int j = 0; j < 4; j++)
                out[(size_t)(rbase + j) * N + cidx] = acc[mi][ni][j] * sc + bs;
        }
    }
}

// ---------------------------------------------------------------------------
extern "C" void kernel_launch(void* const* d_in, const int* in_sizes, int n_in,
                              void* d_out, int out_size, void* d_ws, size_t ws_size,
                              hipStream_t stream) {
    const float* x        = (const float*)d_in[0];
    const float* w        = (const float*)d_in[1];
    const float* bias     = (const float*)d_in[2];
    const float* in_scale = (const float*)d_in[3];
    const float* w_scales = (const float*)d_in[4];
    float* out = (float*)d_out;

    const int N = in_sizes[2];               // 4096
    const int K = in_sizes[1] / N;           // 4096
    const int M = in_sizes[0] / K;           // 16384
    const int CHUNKS = in_sizes[4];          // 4
    const int ocPerChunk = N / CHUNKS;       // 1024

    uint8_t* xq = (uint8_t*)d_ws;            // M*K bytes
    uint8_t* wq = xq + (size_t)M * K;        // N*K bytes (fragment-shuffled)

    const int xn16 = (int)(((size_t)M * K) / 16);

    quant_x_kernel<<<2048, 256, 0, stream>>>(x, in_scale, (uint4*)xq, xn16);
    quant_w_kernel<<<2048, 256, 0, stream>>>(w, w_scales, wq, N, K, ocPerChunk);

    const int nblk = (M / BM) * (N / BN);    // 64 * 16 = 1024
    gemm_fp8_kernel<<<dim3(nblk), 512, 0, stream>>>(xq, wq, bias, in_scale,
                                                    w_scales, out, M, N, K,
                                                    ocPerChunk);
}

// Round 9
// 1664.052 us; speedup vs baseline: 1.0659x; 1.0659x over previous
//
#include <hip/hip_runtime.h>
#include <stdint.h>

#define E4M3_MAX 448.0f

typedef float f32x4 __attribute__((ext_vector_type(4)));
typedef int   i32x4 __attribute__((ext_vector_type(4)));
typedef int   i32x8 __attribute__((ext_vector_type(8)));

// ---------------------------------------------------------------------------
// async global -> LDS, 16 bytes per lane. LDS dest stays LINEAR (HW
// constraint); T2 swizzle applied by pre-swizzling the GLOBAL source column
// and swizzling the LDS READ offset with the same involution (rule #21).
// ---------------------------------------------------------------------------
__device__ __forceinline__ void gload_lds16(const void* g, void* l) {
    __builtin_amdgcn_global_load_lds(
        (__attribute__((address_space(1))) void*)(void*)g,
        (__attribute__((address_space(3))) void*)l,
        16, 0, 0);
}

__device__ __forceinline__ uint32_t quant4(float a, float b, float c, float d) {
    a = fminf(fmaxf(a, -E4M3_MAX), E4M3_MAX);
    b = fminf(fmaxf(b, -E4M3_MAX), E4M3_MAX);
    c = fminf(fmaxf(c, -E4M3_MAX), E4M3_MAX);
    d = fminf(fmaxf(d, -E4M3_MAX), E4M3_MAX);
    int q = 0;
    q = __builtin_amdgcn_cvt_pk_fp8_f32(a, b, q, false);
    q = __builtin_amdgcn_cvt_pk_fp8_f32(c, d, q, true);
    return (uint32_t)q;
}

__global__ void quant_x_kernel(const float* __restrict__ x,
                               const float* __restrict__ scale_p,
                               uint4* __restrict__ xq, int n16) {
    const float inv = 1.0f / scale_p[0];
    const int stride = gridDim.x * blockDim.x;
    for (int i = blockIdx.x * blockDim.x + threadIdx.x; i < n16; i += stride) {
        const float4* p = (const float4*)x + (size_t)i * 4;
        float4 v0 = p[0], v1 = p[1], v2 = p[2], v3 = p[3];
        uint4 q;
        q.x = quant4(v0.x * inv, v0.y * inv, v0.z * inv, v0.w * inv);
        q.y = quant4(v1.x * inv, v1.y * inv, v1.z * inv, v1.w * inv);
        q.z = quant4(v2.x * inv, v2.y * inv, v2.z * inv, v2.w * inv);
        q.w = quant4(v3.x * inv, v3.y * inv, v3.z * inv, v3.w * inv);
        xq[i] = q;
    }
}

// ---------------------------------------------------------------------------
// quantize w into MFMA-FRAGMENT-SHUFFLED layout so the GEMM can load B
// fragments directly global->register with perfectly coalesced dwordx4.
// Element (n, k):  nf=n>>4, r=n&15, kt=k>>7, kg=(k>>5)&3, koff=k&31
//   dst_byte = ((nf*nkt + kt)*64 + kg*16 + r)*32 + koff
// ---------------------------------------------------------------------------
__global__ void quant_w_kernel(const float* __restrict__ w,
                               const float* __restrict__ wsc,
                               uint8_t* __restrict__ wq,
                               int Nrows, int K, int chunkRows) {
    const int nkt = K >> 7;
    const int n32 = Nrows * (K >> 5);
    const int stride = gridDim.x * blockDim.x;
    for (int i = blockIdx.x * blockDim.x + threadIdx.x; i < n32; i += stride) {
        const int n  = i % Nrows;
        const int k0 = (i / Nrows) << 5;
        const float inv = 1.0f / wsc[n / chunkRows];
        const float4* p = (const float4*)(w + (size_t)n * K + k0);
        uint4 qa, qb;
        {
            float4 v0 = p[0], v1 = p[1], v2 = p[2], v3 = p[3];
            qa.x = quant4(v0.x * inv, v0.y * inv, v0.z * inv, v0.w * inv);
            qa.y = quant4(v1.x * inv, v1.y * inv, v1.z * inv, v1.w * inv);
            qa.z = quant4(v2.x * inv, v2.y * inv, v2.z * inv, v2.w * inv);
            qa.w = quant4(v3.x * inv, v3.y * inv, v3.z * inv, v3.w * inv);
        }
        {
            float4 v0 = p[4], v1 = p[5], v2 = p[6], v3 = p[7];
            qb.x = quant4(v0.x * inv, v0.y * inv, v0.z * inv, v0.w * inv);
            qb.y = quant4(v1.x * inv, v1.y * inv, v1.z * inv, v1.w * inv);
            qb.z = quant4(v2.x * inv, v2.y * inv, v2.z * inv, v2.w * inv);
            qb.w = quant4(v3.x * inv, v3.y * inv, v3.z * inv, v3.w * inv);
        }
        const int kt = k0 >> 7, kg = (k0 >> 5) & 3, r = n & 15, nf = n >> 4;
        uint8_t* dst = wq + (((size_t)nf * nkt + kt) * 64 + kg * 16 + r) * 32;
        *(uint4*)dst = qa;
        *(uint4*)(dst + 16) = qb;
    }
}

__device__ __forceinline__ i32x8 read_frag(const uint8_t* base, int o0, int o1) {
    i32x4 lo = *(const i32x4*)(base + o0);
    i32x4 hi = *(const i32x4*)(base + o1);
    return __builtin_shufflevector(lo, hi, 0, 1, 2, 3, 4, 5, 6, 7);
}

__device__ __forceinline__ i32x8 load_bfrag(const uint8_t* p) {
    i32x4 lo = *(const i32x4*)p;
    i32x4 hi = *(const i32x4*)(p + 16);
    return __builtin_shufflevector(lo, hi, 0, 1, 2, 3, 4, 5, 6, 7);
}

#define MFMA_MX(a, b, c) \
    __builtin_amdgcn_mfma_scale_f32_16x16x128_f8f6f4( \
        (a), (b), (c), 0, 0, 0, 0x7F7F7F7F, 0, 0x7F7F7F7F)

#define WAIT_LGKM(n)                                            \
    do {                                                        \
        asm volatile("s_waitcnt lgkmcnt(" #n ")" ::: "memory"); \
        __builtin_amdgcn_sched_barrier(0);                      \
    } while (0)

#define WAIT_VM(n)                                              \
    do {                                                        \
        asm volatile("s_waitcnt vmcnt(" #n ")" ::: "memory");   \
        __builtin_amdgcn_sched_barrier(0);                      \
    } while (0)

// ---------------------------------------------------------------------------
// fp8-MX GEMM, 256x256 tile, 8 waves (2Mx4N), wave-tile 128x64.
// Round-9 = round-8 schedule, spill-proof:
//   - B(t) in NAMED registers bc0..bc3; B(t+1) prefetched into bn0..bn3
//     (no arrays, no lambda refs -> SROA-safe; K-loop unrolled x2 by macro)
//   - A in double-buffered LDS (64 KB), rolling 4-frag lgkm(4) pipeline
//   - vmcnt ledger (issue order: stage 4, then B(t+1) 8):
//       g0:      vmcnt(12) -> retires B(t) only
//       iterend: vmcnt(8)  -> retires stage(t+1); B(t+1) crosses barrier
// ---------------------------------------------------------------------------
#define BM 256
#define BN 256
#define BKB 128

#define TILE_ITER(T, BC0, BC1, BC2, BC3, BN0, BN1, BN2, BN3)                   \
    do {                                                                       \
        const int  cur = (T) & 1;                                              \
        const bool pre = ((T) + 1 < nkt);                                      \
        const uint8_t* pa = &As[cur][0] + (wm * 128 + lr) * BKB;               \
        if (pre) {                                                             \
            stage(cur ^ 1, ((T) + 1) * BKB);                                   \
            __builtin_amdgcn_sched_barrier(0);                                 \
            const uint8_t* bb = bbase + (size_t)((T) + 1) * 2048;              \
            BN0 = load_bfrag(bb);                                              \
            BN1 = load_bfrag(bb + (size_t)nkt * 2048);                         \
            BN2 = load_bfrag(bb + (size_t)nkt * 4096);                         \
            BN3 = load_bfrag(bb + (size_t)nkt * 6144);                         \
            __builtin_amdgcn_sched_barrier(0);                                 \
        }                                                                      \
        /* A pipeline: issue frags 0..3 (8 ds_read_b128) */                    \
        i32x8 a0 = read_frag(pa,            off0, off1);                       \
        i32x8 a1 = read_frag(pa + 16 * BKB, off0, off1);                       \
        i32x8 a2 = read_frag(pa + 32 * BKB, off0, off1);                       \
        i32x8 a3 = read_frag(pa + 48 * BKB, off0, off1);                       \
        if (pre) { WAIT_VM(12); } else { WAIT_VM(0); }                         \
        WAIT_LGKM(4); /* a0,a1 ready; a2,a3 in flight */                       \
        __builtin_amdgcn_s_setprio(1);                                         \
        acc[0][0] = MFMA_MX(a0, BC0, acc[0][0]);                               \
        acc[0][1] = MFMA_MX(a0, BC1, acc[0][1]);                               \
        acc[0][2] = MFMA_MX(a0, BC2, acc[0][2]);                               \
        acc[0][3] = MFMA_MX(a0, BC3, acc[0][3]);                               \
        acc[1][0] = MFMA_MX(a1, BC0, acc[1][0]);                               \
        acc[1][1] = MFMA_MX(a1, BC1, acc[1][1]);                               \
        acc[1][2] = MFMA_MX(a1, BC2, acc[1][2]);                               \
        acc[1][3] = MFMA_MX(a1, BC3, acc[1][3]);                               \
        __builtin_amdgcn_s_setprio(0);                                         \
        i32x8 a4 = read_frag(pa + 64 * BKB, off0, off1);                       \
        i32x8 a5 = read_frag(pa + 80 * BKB, off0, off1);                       \
        WAIT_LGKM(4); /* a2,a3 ready; a4,a5 in flight */                       \
        __builtin_amdgcn_s_setprio(1);                                         \
        acc[2][0] = MFMA_MX(a2, BC0, acc[2][0]);                               \
        acc[2][1] = MFMA_MX(a2, BC1, acc[2][1]);                               \
        acc[2][2] = MFMA_MX(a2, BC2, acc[2][2]);                               \
        acc[2][3] = MFMA_MX(a2, BC3, acc[2][3]);                               \
        acc[3][0] = MFMA_MX(a3, BC0, acc[3][0]);                               \
        acc[3][1] = MFMA_MX(a3, BC1, acc[3][1]);                               \
        acc[3][2] = MFMA_MX(a3, BC2, acc[3][2]);                               \
        acc[3][3] = MFMA_MX(a3, BC3, acc[3][3]);                               \
        __builtin_amdgcn_s_setprio(0);                                         \
        i32x8 a6 = read_frag(pa + 96 * BKB,  off0, off1);                      \
        i32x8 a7 = read_frag(pa + 112 * BKB, off0, off1);                      \
        WAIT_LGKM(4); /* a4,a5 ready; a6,a7 in flight */                       \
        __builtin_amdgcn_s_setprio(1);                                         \
        acc[4][0] = MFMA_MX(a4, BC0, acc[4][0]);                               \
        acc[4][1] = MFMA_MX(a4, BC1, acc[4][1]);                               \
        acc[4][2] = MFMA_MX(a4, BC2, acc[4][2]);                               \
        acc[4][3] = MFMA_MX(a4, BC3, acc[4][3]);                               \
        acc[5][0] = MFMA_MX(a5, BC0, acc[5][0]);                               \
        acc[5][1] = MFMA_MX(a5, BC1, acc[5][1]);                               \
        acc[5][2] = MFMA_MX(a5, BC2, acc[5][2]);                               \
        acc[5][3] = MFMA_MX(a5, BC3, acc[5][3]);                               \
        __builtin_amdgcn_s_setprio(0);                                         \
        WAIT_LGKM(0); /* a6,a7 ready */                                        \
        __builtin_amdgcn_s_setprio(1);                                         \
        acc[6][0] = MFMA_MX(a6, BC0, acc[6][0]);                               \
        acc[6][1] = MFMA_MX(a6, BC1, acc[6][1]);                               \
        acc[6][2] = MFMA_MX(a6, BC2, acc[6][2]);                               \
        acc[6][3] = MFMA_MX(a6, BC3, acc[6][3]);                               \
        acc[7][0] = MFMA_MX(a7, BC0, acc[7][0]);                               \
        acc[7][1] = MFMA_MX(a7, BC1, acc[7][1]);                               \
        acc[7][2] = MFMA_MX(a7, BC2, acc[7][2]);                               \
        acc[7][3] = MFMA_MX(a7, BC3, acc[7][3]);                               \
        __builtin_amdgcn_s_setprio(0);                                         \
        if (pre) { WAIT_VM(8); } else { WAIT_VM(0); }                          \
        __builtin_amdgcn_s_barrier();                                          \
    } while (0)

__global__ __launch_bounds__(512, 2) void gemm_fp8_kernel(
    const uint8_t* __restrict__ Aq, const uint8_t* __restrict__ Bq,
    const float* __restrict__ bias, const float* __restrict__ isp,
    const float* __restrict__ wsc, float* __restrict__ out,
    int M, int N, int K, int ocPerChunk) {
    __shared__ __align__(16) uint8_t As[2][BM * BKB];   // A only, 2 x 32 KB

    const int tid  = threadIdx.x;
    const int lane = tid & 63;
    const int wid  = tid >> 6;   // 0..7
    const int wm   = wid >> 2;   // 0..1  (M half)
    const int wn   = wid & 3;    // 0..3  (N quarter)

    // T1 XCD swizzle, by-inner chunking: consecutive blocks on an XCD share
    // bx -> the XCD's CUs work on few B-panels (L2-fit).
    const int nbx   = N / BN;
    const int nby   = M / BM;
    const int chunk = nby >> 3;            // by-rows per XCD
    const int xcd   = blockIdx.x & 7;
    const int local = blockIdx.x >> 3;
    const int bx    = local / chunk;
    const int by    = xcd * chunk + (local % chunk);
    const int m0    = by * BM;
    const int n0    = bx * BN;

    const int lr   = lane & 15;
    const int sw   = (lr & 7) << 4;
    const int off0 = ((lane >> 4) * 32) ^ sw;
    const int off1 = off0 ^ 16;

    f32x4 acc[8][4] = {};

    const int nkt = K / BKB;

    // B fragment base: frag ni of wave wn at tile t lives at
    // bbase + (ni*nkt + t)*2048, lane-contiguous 32 B.
    const uint8_t* bbase =
        Bq + ((size_t)((n0 >> 4) + wn * 4) * nkt) * 2048 + lane * 32;

    // stage A K-tile (k-offset kt) into buffer b: 4 x gload_lds16 per thread
    auto stage = [&](int b, int kt) {
#pragma unroll
        for (int i = 0; i < 4; ++i) {
            const int idx = i * 512 + tid;                 // 0..2047
            const int row = idx >> 3;                      // 0..255
            const int col = ((idx & 7) * 16) ^ ((row & 7) << 4);
            gload_lds16(Aq + (size_t)(m0 + row) * K + kt + col,
                        &As[b][0] + idx * 16);
        }
    };

    i32x8 bc0, bc1, bc2, bc3, bn0, bn1, bn2, bn3;

    // prologue: A tile 0 -> LDS, B tile 0 -> bc*
    stage(0, 0);
    bc0 = load_bfrag(bbase);
    bc1 = load_bfrag(bbase + (size_t)nkt * 2048);
    bc2 = load_bfrag(bbase + (size_t)nkt * 4096);
    bc3 = load_bfrag(bbase + (size_t)nkt * 6144);
    asm volatile("s_waitcnt vmcnt(0)" ::: "memory");
    __builtin_amdgcn_s_barrier();

    for (int t = 0; t < nkt; t += 2) {
        TILE_ITER(t,     bc0, bc1, bc2, bc3, bn0, bn1, bn2, bn3);
        TILE_ITER(t + 1, bn0, bn1, bn2, bn3, bc0, bc1, bc2, bc3);
    }

    // ---- epilogue: dequant + bias (C/D: col=lane&15, row=(lane>>4)*4+j) ----
    const float is = isp[0];
#pragma unroll
    for (int ni = 0; ni < 4; ni++) {
        const int cidx = n0 + wn * 64 + ni * 16 + lr;
        const float sc = is * wsc[cidx / ocPerChunk];
        const float bs = bias[cidx];
#pragma unroll
        for (int mi = 0; mi < 8; mi++) {
            const int rbase = m0 + wm * 128 + mi * 16 + (lane >> 4) * 4;
#pragma unroll
            for (int j = 0; j < 4; j++)
                out[(size_t)(rbase + j) * N + cidx] = acc[mi][ni][j] * sc + bs;
        }
    }
}

// ---------------------------------------------------------------------------
extern "C" void kernel_launch(void* const* d_in, const int* in_sizes, int n_in,
                              void* d_out, int out_size, void* d_ws, size_t ws_size,
                              hipStream_t stream) {
    const float* x        = (const float*)d_in[0];
    const float* w        = (const float*)d_in[1];
    const float* bias     = (const float*)d_in[2];
    const float* in_scale = (const float*)d_in[3];
    const float* w_scales = (const float*)d_in[4];
    float* out = (float*)d_out;

    const int N = in_sizes[2];               // 4096
    const int K = in_sizes[1] / N;           // 4096
    const int M = in_sizes[0] / K;           // 16384
    const int CHUNKS = in_sizes[4];          // 4
    const int ocPerChunk = N / CHUNKS;       // 1024

    uint8_t* xq = (uint8_t*)d_ws;            // M*K bytes
    uint8_t* wq = xq + (size_t)M * K;        // N*K bytes (fragment-shuffled)

    const int xn16 = (int)(((size_t)M * K) / 16);

    quant_x_kernel<<<2048, 256, 0, stream>>>(x, in_scale, (uint4*)xq, xn16);
    quant_w_kernel<<<2048, 256, 0, stream>>>(w, w_scales, wq, N, K, ocPerChunk);

    const int nblk = (M / BM) * (N / BN);    // 64 * 16 = 1024
    gemm_fp8_kernel<<<dim3(nblk), 512, 0, stream>>>(xq, wq, bias, in_scale,
                                                    w_scales, out, M, N, K,
                                                    ocPerChunk);
}